// Round 9
// baseline (2974.861 us; speedup 1.0000x reference)
//
#include <hip/hip_runtime.h>
#include <hip/hip_fp16.h>

#define TSEQ   2048
#define NB     64
#define NE     256
#define NH     256
#define NG     768
#define TCH    64
#define NCHUNK (TSEQ / TCH)
#define POOL_BYTES 103936

typedef _Float16 f16x8 __attribute__((ext_vector_type(8)));
typedef float    f32x4 __attribute__((ext_vector_type(4)));
typedef unsigned u32x4 __attribute__((ext_vector_type(4)));

// ---------------------------------------------------------------------------
// prep_whh: pack w_hh into per-(j,s)-contiguous fp16 blocks for the rec asm.
// Thread (j, s) owns 768 B at byte (s*256 + j)*768: quad n = g*16 + i
// (g in {r,z,n}), u32 c = fp16 pair of whh[g*256+j][s*128 + i*8 + 2c (,+1)].
// ---------------------------------------------------------------------------
__global__ void prep_whh(const float* __restrict__ whh, unsigned* __restrict__ w16) {
  int idx = blockIdx.x * 256 + threadIdx.x;        // 0..98303
  if (idx >= 98304) return;
  int c    = idx & 3;
  int i    = (idx >> 2) & 15;
  int g    = (idx >> 6) % 3;
  int rest = idx / 192;                            // s*256 + j
  int j    = rest & 255;
  int s    = rest >> 8;
  int k    = s * 128 + i * 8 + 2 * c;
  const float* src = whh + (size_t)(g * 256 + j) * 256 + k;
  union { _Float16 h[2]; unsigned u; } p;
  p.h[0] = (_Float16)src[0];
  p.h[1] = (_Float16)src[1];
  w16[idx] = p.u;
}

// prep_wih: w_ih fp32 [768][256] -> fp16 row-major (u32 = pair).
__global__ void prep_wih(const float* __restrict__ wih, unsigned* __restrict__ wih16) {
  int idx = blockIdx.x * 256 + threadIdx.x;        // 0..98303
  if (idx >= 98304) return;
  union { _Float16 h[2]; unsigned u; } p;
  p.h[0] = (_Float16)wih[2 * idx];
  p.h[1] = (_Float16)wih[2 * idx + 1];
  wih16[idx] = p.u;
}

// ---- rec asm building blocks ----------------------------------------------
#define WLD(D0,D1,OFF) \
  "global_load_dwordx4 v[" D0 ":" D1 "], %[wof], %[wptr] offset:" OFF "\n\t"

#define RL4(Q,S0,S1,S2,S3) \
  "v_readlane_b32 s" #S0 ", v32, " #Q "\n\t" \
  "v_readlane_b32 s" #S1 ", v33, " #Q "\n\t" \
  "v_readlane_b32 s" #S2 ", v34, " #Q "\n\t" \
  "v_readlane_b32 s" #S3 ", v35, " #Q "\n\t"

#define DQS(S,R,Z,N) \
  "v_dot2_f32_f16 v16, s" #S ", v" #R ", v16\n\t" \
  "v_dot2_f32_f16 v17, s" #S ", v" #Z ", v17\n\t" \
  "v_dot2_f32_f16 v18, s" #S ", v" #N ", v18\n\t"

#define RL_ALL \
  RL4(0,36,37,38,39)   RL4(1,40,41,42,43)   RL4(2,44,45,46,47)   RL4(3,48,49,50,51) \
  RL4(4,52,53,54,55)   RL4(5,56,57,58,59)   RL4(6,60,61,62,63)   RL4(7,64,65,66,67) \
  RL4(8,68,69,70,71)   RL4(9,72,73,74,75)   RL4(10,76,77,78,79)  RL4(11,80,81,82,83) \
  RL4(12,84,85,86,87)  RL4(13,88,89,90,91)  RL4(14,92,93,94,95)  RL4(15,96,97,98,99)

#define DQ_ALL \
  DQS(36,64,128,192) DQS(37,65,129,193) DQS(38,66,130,194) DQS(39,67,131,195) \
  DQS(40,68,132,196) DQS(41,69,133,197) DQS(42,70,134,198) DQS(43,71,135,199) \
  DQS(44,72,136,200) DQS(45,73,137,201) DQS(46,74,138,202) DQS(47,75,139,203) \
  DQS(48,76,140,204) DQS(49,77,141,205) DQS(50,78,142,206) DQS(51,79,143,207) \
  DQS(52,80,144,208) DQS(53,81,145,209) DQS(54,82,146,210) DQS(55,83,147,211) \
  DQS(56,84,148,212) DQS(57,85,149,213) DQS(58,86,150,214) DQS(59,87,151,215) \
  DQS(60,88,152,216) DQS(61,89,153,217) DQS(62,90,154,218) DQS(63,91,155,219) \
  DQS(64,92,156,220) DQS(65,93,157,221) DQS(66,94,158,222) DQS(67,95,159,223) \
  DQS(68,96,160,224) DQS(69,97,161,225) DQS(70,98,162,226) DQS(71,99,163,227) \
  DQS(72,100,164,228) DQS(73,101,165,229) DQS(74,102,166,230) DQS(75,103,167,231) \
  DQS(76,104,168,232) DQS(77,105,169,233) DQS(78,106,170,234) DQS(79,107,171,235) \
  DQS(80,108,172,236) DQS(81,109,173,237) DQS(82,110,174,238) DQS(83,111,175,239) \
  DQS(84,112,176,240) DQS(85,113,177,241) DQS(86,114,178,242) DQS(87,115,179,243) \
  DQS(88,116,180,244) DQS(89,117,181,245) DQS(90,118,182,246) DQS(91,119,183,247) \
  DQS(92,120,184,248) DQS(93,121,185,249) DQS(94,122,186,250) DQS(95,123,187,251) \
  DQS(96,124,188,252) DQS(97,125,189,253) DQS(98,126,190,254) DQS(99,127,191,255)

// one timestep. BUF/NBUF = h read/write buffer byte offsets ("0"/"1024").
#define STEP(BUF,NBUF) \
  "global_load_dword v12, v3, %[gip]\n\t" \
  "global_load_dword v13, v3, %[gip] offset:1024\n\t" \
  "global_load_dword v14, v3, %[gip] offset:2048\n\t" \
  "v_add_u32 v3, 0x30000, v3\n\t" \
  "v_mov_b32 v16, 0\n\t" \
  "v_mov_b32 v17, 0\n\t" \
  "v_mov_b32 v18, 0\n\t" \
  "ds_read_b128 v[32:35], v2 offset:" BUF "\n\t" \
  "s_waitcnt lgkmcnt(0)\n\t" \
  RL_ALL \
  DQ_ALL \
  "ds_write_b32 v29, v16\n\t" \
  "ds_write_b32 v29, v17 offset:1024\n\t" \
  "ds_write_b32 v29, v18 offset:2048\n\t" \
  "s_waitcnt lgkmcnt(0)\n\t" \
  "s_barrier\n\t" \
  "ds_read_b32 v20, v30\n\t" \
  "ds_read_b32 v21, v30 offset:1024\n\t" \
  "ds_read_b32 v22, v30 offset:2048\n\t" \
  "s_waitcnt lgkmcnt(0)\n\t" \
  "v_add_f32 v16, v16, v20\n\t" \
  "v_add_f32 v17, v17, v21\n\t" \
  "v_add_f32 v18, v18, v22\n\t" \
  "s_waitcnt vmcnt(0)\n\t" \
  "v_add_f32 v20, v12, v16\n\t" \
  "v_mul_f32 v20, 0xbfb8aa3b, v20\n\t" \
  "v_exp_f32 v20, v20\n\t" \
  "v_add_f32 v21, v13, v17\n\t" \
  "v_mul_f32 v21, 0xbfb8aa3b, v21\n\t" \
  "v_exp_f32 v21, v21\n\t" \
  "v_add_f32 v20, 1.0, v20\n\t" \
  "v_rcp_f32 v20, v20\n\t" \
  "v_add_f32 v21, 1.0, v21\n\t" \
  "v_rcp_f32 v21, v21\n\t" \
  "v_add_f32 v22, v18, v28\n\t" \
  "v_fma_f32 v22, v20, v22, v14\n\t" \
  "v_min_f32 v22, 0x41700000, v22\n\t" \
  "v_mul_f32 v22, 0x4038aa3b, v22\n\t" \
  "v_exp_f32 v22, v22\n\t" \
  "s_nop 1\n\t" \
  "v_add_f32 v23, -1.0, v22\n\t" \
  "v_add_f32 v22, 1.0, v22\n\t" \
  "v_rcp_f32 v22, v22\n\t" \
  "s_nop 1\n\t" \
  "v_mul_f32 v22, v23, v22\n\t" \
  "v_sub_f32 v23, v24, v22\n\t" \
  "v_fma_f32 v24, v21, v23, v22\n\t" \
  "v_cvt_f16_f32 v25, v24\n\t" \
  "ds_write_b16 v31, v25 offset:" NBUF "\n\t" \
  "s_waitcnt lgkmcnt(0)\n\t" \
  "s_barrier\n\t"

// ---------------------------------------------------------------------------
// Fused per-chunk kernel, 512 threads, ~104KB LDS pool (1 WG/CU).
//   blocks [0, rec_count)            : recurrence (1 block = 1 batch element)
//   blocks [rec_count, rec_count+192): gi GEMM (MFMA fp16) for the NEXT chunk
// rec: wave w -> (s = w>>2, j = (w&3)*64 + lane). Weights v64-v255 pinned;
// h-half wave-uniform in SGPRs s36-s99 via 1 ds_read_b128 + 64 readlanes.
// ---------------------------------------------------------------------------
__global__ __launch_bounds__(512)
void fused_kernel(const int* __restrict__ seq, const float* __restrict__ emb,
                  const unsigned* __restrict__ wih16, const float* __restrict__ bih,
                  const float* __restrict__ bhh, const unsigned* __restrict__ w16,
                  const float* __restrict__ rec_gi, float* __restrict__ gi_dst,
                  int gi_t0, float* __restrict__ h_state, float* __restrict__ out,
                  int rec_count, int chunk)
{
  __shared__ __align__(16) char smem[POOL_BYTES];
  const int tid = threadIdx.x;

  if ((int)blockIdx.x < rec_count) {
    // ======================= recurrence (asm) =======================
    const int b    = blockIdx.x;
    const int lane = tid & 63;
    const int w    = tid >> 6;
    const int s_   = w >> 2;                 // k-half
    const int j    = (w & 3) * 64 + lane;    // hidden index 0..255

    float h0 = 0.f;
    if (chunk != 0) h0 = h_state[b * NH + j];
    const float bnv = bhh[2 * NH + j];
    ((_Float16*)smem)[j] = (_Float16)h0;     // h buffer 0 (dup writes same value)
    __syncthreads();

    const unsigned pool0 = (unsigned)(uintptr_t)(smem);
    const unsigned hrd = pool0 + s_ * 256 + (lane & 15) * 16;  // h quad read addr
    const unsigned hwa = pool0 + j * 2;                        // h write addr
    const unsigned pwr = pool0 + 2048 + s_ * 3072 + j * 4;     // partial write
    const unsigned prd = pool0 + 2048 + (1 - s_) * 3072 + j * 4; // partner read
    const unsigned gio = j * 4;
    const unsigned wof = (unsigned)(s_ * 256 + j) * 768;
    const float* gib = rec_gi + (size_t)b * NG;

    float hout;
    asm volatile(
      "v_mov_b32 v2, %[hrd]\n\t"
      "v_mov_b32 v3, %[gio]\n\t"
      "v_mov_b32 v24, %[h0]\n\t"
      "v_mov_b32 v28, %[bn]\n\t"
      "v_mov_b32 v29, %[pwr]\n\t"
      "v_mov_b32 v30, %[prd]\n\t"
      "v_mov_b32 v31, %[hwa]\n\t"
      WLD("64","67","0")    WLD("68","71","16")   WLD("72","75","32")   WLD("76","79","48")
      WLD("80","83","64")   WLD("84","87","80")   WLD("88","91","96")   WLD("92","95","112")
      WLD("96","99","128")  WLD("100","103","144")WLD("104","107","160")WLD("108","111","176")
      WLD("112","115","192")WLD("116","119","208")WLD("120","123","224")WLD("124","127","240")
      WLD("128","131","256")WLD("132","135","272")WLD("136","139","288")WLD("140","143","304")
      WLD("144","147","320")WLD("148","151","336")WLD("152","155","352")WLD("156","159","368")
      WLD("160","163","384")WLD("164","167","400")WLD("168","171","416")WLD("172","175","432")
      WLD("176","179","448")WLD("180","183","464")WLD("184","187","480")WLD("188","191","496")
      WLD("192","195","512")WLD("196","199","528")WLD("200","203","544")WLD("204","207","560")
      WLD("208","211","576")WLD("212","215","592")WLD("216","219","608")WLD("220","223","624")
      WLD("224","227","640")WLD("228","231","656")WLD("232","235","672")WLD("236","239","688")
      WLD("240","243","704")WLD("244","247","720")WLD("248","251","736")WLD("252","255","752")
      "s_waitcnt vmcnt(0)\n\t"
      "s_mov_b32 s20, 32\n\t"
      "1:\n\t"
      STEP("0","1024")
      STEP("1024","0")
      "s_sub_u32 s20, s20, 1\n\t"
      "s_cmp_lg_u32 s20, 0\n\t"
      "s_cbranch_scc1 1b\n\t"
      "v_mov_b32 %[hout], v24\n\t"
      : [hout] "=v"(hout)
      : [hrd] "v"(hrd), [gio] "v"(gio), [h0] "v"(h0), [bn] "v"(bnv),
        [pwr] "v"(pwr), [prd] "v"(prd), [hwa] "v"(hwa), [wof] "v"(wof),
        [wptr] "s"(w16), [gip] "s"(gib)
      : "memory","scc","s20",
        "s36","s37","s38","s39","s40","s41","s42","s43","s44","s45","s46","s47",
        "s48","s49","s50","s51","s52","s53","s54","s55","s56","s57","s58","s59",
        "s60","s61","s62","s63","s64","s65","s66","s67","s68","s69","s70","s71",
        "s72","s73","s74","s75","s76","s77","s78","s79","s80","s81","s82","s83",
        "s84","s85","s86","s87","s88","s89","s90","s91","s92","s93","s94","s95",
        "s96","s97","s98","s99",
        "v2","v3","v12","v13","v14","v16","v17","v18","v20","v21","v22","v23",
        "v24","v25","v28","v29","v30","v31","v32","v33","v34","v35",
        "v64","v65","v66","v67","v68","v69","v70","v71","v72","v73","v74","v75",
        "v76","v77","v78","v79","v80","v81","v82","v83","v84","v85","v86","v87",
        "v88","v89","v90","v91","v92","v93","v94","v95","v96","v97","v98","v99",
        "v100","v101","v102","v103","v104","v105","v106","v107","v108","v109",
        "v110","v111","v112","v113","v114","v115","v116","v117","v118","v119",
        "v120","v121","v122","v123","v124","v125","v126","v127","v128","v129",
        "v130","v131","v132","v133","v134","v135","v136","v137","v138","v139",
        "v140","v141","v142","v143","v144","v145","v146","v147","v148","v149",
        "v150","v151","v152","v153","v154","v155","v156","v157","v158","v159",
        "v160","v161","v162","v163","v164","v165","v166","v167","v168","v169",
        "v170","v171","v172","v173","v174","v175","v176","v177","v178","v179",
        "v180","v181","v182","v183","v184","v185","v186","v187","v188","v189",
        "v190","v191","v192","v193","v194","v195","v196","v197","v198","v199",
        "v200","v201","v202","v203","v204","v205","v206","v207","v208","v209",
        "v210","v211","v212","v213","v214","v215","v216","v217","v218","v219",
        "v220","v221","v222","v223","v224","v225","v226","v227","v228","v229",
        "v230","v231","v232","v233","v234","v235","v236","v237","v238","v239",
        "v240","v241","v242","v243","v244","v245","v246","v247","v248","v249",
        "v250","v251","v252","v253","v254","v255");

    h_state[b * NH + j] = hout;              // dup across s: same value
    if (out) out[b * NH + j] = hout;
  } else {
    // ======================= gi GEMM (MFMA fp16) ==========================
    if (gi_dst == nullptr) return;
    _Float16* xs   = (_Float16*)smem;              // [64][264]  33,792 B
    _Float16* wsh  = (_Float16*)(smem + 33792);    // [256][136] 69,632 B
    int*      tok  = (int*)(smem + 103424);        //    256 B
    const int gb = blockIdx.x - rec_count;   // 0..191
    const int tl = gb & 63;
    const int g0 = (gb >> 6) * 256;
    const int t  = gi_t0 + tl;
    if (tid < 64) tok[tid] = seq[tid * TSEQ + t];
    __syncthreads();

    // stage x (fp32 -> fp16), full K=256
    {
      const int r = tid >> 3, cb = tid & 7;
      const float* src = emb + (size_t)tok[r] * NE + cb * 32;
      _Float16* dst = xs + r * 264 + cb * 32;
#pragma unroll
      for (int m = 0; m < 8; ++m) {
        float4 v = *(const float4*)(src + m * 4);
        union { _Float16 h[4]; uint2 u; } p;
        p.h[0] = (_Float16)v.x; p.h[1] = (_Float16)v.y;
        p.h[2] = (_Float16)v.z; p.h[3] = (_Float16)v.w;
        *(uint2*)(dst + m * 4) = p.u;
      }
    }

    const int w  = tid >> 6, l = tid & 63;
    const int lr = l & 15, lk = (l >> 4) * 8;
    f32x4 acc[4][2] = {};

#pragma unroll
    for (int kh = 0; kh < 2; ++kh) {
      // stage w_ih half [256 g][128 k] fp16
      {
        if (kh) __syncthreads();             // protect wsh from prev readers
        const int g = tid >> 1, hb = tid & 1;
        const unsigned* srcu = wih16 + ((size_t)(g0 + g) * 128 + kh * 64 + hb * 32);
        _Float16* dsth = wsh + g * 136 + hb * 64;
#pragma unroll
        for (int i = 0; i < 8; ++i)
          *(u32x4*)(dsth + i * 8) = *(const u32x4*)(srcu + i * 4);
      }
      __syncthreads();
#pragma unroll
      for (int ks = 0; ks < 4; ++ks) {
        f16x8 a[4], bfr[2];
#pragma unroll
        for (int mt = 0; mt < 4; ++mt)
          a[mt] = *(const f16x8*)(xs + (mt * 16 + lr) * 264 + kh * 128 + ks * 32 + lk);
#pragma unroll
        for (int n = 0; n < 2; ++n)
          bfr[n] = *(const f16x8*)(wsh + ((w * 2 + n) * 16 + lr) * 136 + ks * 32 + lk);
#pragma unroll
        for (int mt = 0; mt < 4; ++mt)
#pragma unroll
          for (int n = 0; n < 2; ++n)
            acc[mt][n] = __builtin_amdgcn_mfma_f32_16x16x32_f16(
                a[mt], bfr[n], acc[mt][n], 0, 0, 0);
      }
    }

    // epilogue: C row = batch (m), col = gate (n); add b_ih (+ b_hh for r,z)
    const int rbase = (l >> 4) * 4;
#pragma unroll
    for (int n = 0; n < 2; ++n) {
      const int gcol = g0 + (w * 2 + n) * 16 + lr;
      const float bias = bih[gcol] + (gcol < 2 * NH ? bhh[gcol] : 0.f);
#pragma unroll
      for (int mt = 0; mt < 4; ++mt)
#pragma unroll
        for (int rr = 0; rr < 4; ++rr) {
          const int brow = mt * 16 + rbase + rr;
          gi_dst[((size_t)tl * NB + brow) * NG + gcol] = acc[mt][n][rr] + bias;
        }
    }
  }
}

extern "C" void kernel_launch(void* const* d_in, const int* in_sizes, int n_in,
                              void* d_out, int out_size, void* d_ws, size_t ws_size,
                              hipStream_t stream) {
  (void)in_sizes; (void)n_in; (void)out_size; (void)ws_size;
  const int*   seq = (const int*)d_in[0];
  const float* emb = (const float*)d_in[1];
  const float* wih = (const float*)d_in[2];
  const float* whh = (const float*)d_in[3];
  const float* bih = (const float*)d_in[4];
  const float* bhh = (const float*)d_in[5];
  float* out = (float*)d_out;
  char*  ws  = (char*)d_ws;

  unsigned* w16     = (unsigned*)(ws);                 //   393,216 B
  unsigned* wih16   = (unsigned*)(ws + 393216);        //   393,216 B
  float*    h_state = (float*)(ws + 786432);           //    65,536 B
  float*    gi0     = (float*)(ws + 851968);           // 12,582,912 B
  float*    gi1     = (float*)(ws + 851968 + 12582912);

  prep_whh<<<dim3(384), dim3(256), 0, stream>>>(whh, w16);
  prep_wih<<<dim3(384), dim3(256), 0, stream>>>(wih, wih16);

  // prologue: gi for chunk 0 only
  fused_kernel<<<dim3(192), dim3(512), 0, stream>>>(
      seq, emb, wih16, bih, bhh, w16,
      nullptr, gi0, 0, h_state, nullptr, 0, 0);

  for (int c = 0; c < NCHUNK; ++c) {
    float* rd  = (c & 1) ? gi1 : gi0;
    float* wr_ = (c & 1) ? gi0 : gi1;
    const bool last = (c == NCHUNK - 1);
    const int grid  = last ? NB : NB + 192;
    fused_kernel<<<dim3(grid), dim3(512), 0, stream>>>(
        seq, emb, wih16, bih, bhh, w16,
        rd, last ? nullptr : wr_, (c + 1) * TCH, h_state,
        last ? out : nullptr, NB, c);
  }
}